// Round 3
// baseline (162.443 us; speedup 1.0000x reference)
//
#include <hip/hip_runtime.h>
#include <math.h>

#define BINS   256
#define CH     3
#define NHIST  (CH * BINS)           // 768
#define HW_LOG2_V4 18                // channel of float4 i = (i >> 18) % 3  (H*W = 1<<20)
#define NCOPY  8                     // hist accumulator copies
#define NBLK_T 1024                  // minmax blocks per tensor (2*NBLK_T total)
#define NBLK_H 1536                  // hist blocks

// d_ws layout (unsigned int):
//   [0..3]                          : final min_a, max_a, min_b, max_b (float bits)
//   [4 .. 4 + NCOPY*2*NHIST)        : hist copies: copy c -> [a: NHIST][b: NHIST]
//   [WS_PART .. WS_PART+4*NBLK_T)   : minmax partials {mn,mx} per block (a: first 2*NBLK_T, b: rest)
#define WS_HIST 4
#define WS_PART (4 + NCOPY * 2 * NHIST)   // 12292

__global__ void init_ws_kernel(unsigned int* ws) {
    int i = blockIdx.x * blockDim.x + threadIdx.x;
    for (int j = WS_HIST + i; j < WS_PART; j += gridDim.x * blockDim.x)
        ws[j] = 0u;
}

__device__ __forceinline__ float min4(float4 v) { return fminf(fminf(v.x, v.y), fminf(v.z, v.w)); }
__device__ __forceinline__ float max4(float4 v) { return fmaxf(fmaxf(v.x, v.y), fmaxf(v.z, v.w)); }

// Pass 1: per-block min/max partials. One tensor per block (blocks [0,NBLK_T) -> a,
// [NBLK_T,2*NBLK_T) -> b). 8 loads in flight with 8 independent accumulator chains;
// __launch_bounds__(256,4) gives the regalloc a 128-VGPR budget so it does NOT
// serialize the loads (R1: VGPR=24 forced 1-load-in-flight -> 130us latency-bound).
__global__ __launch_bounds__(256, 4) void minmax_part_kernel(const float4* __restrict__ a,
                                                             const float4* __restrict__ b,
                                                             int n4, unsigned int* __restrict__ part) {
    int bid = blockIdx.x;
    const float4* __restrict__ p = (bid >= NBLK_T) ? b : a;
    int blk = (bid >= NBLK_T) ? bid - NBLK_T : bid;
    int tid = threadIdx.x;
    int stride = NBLK_T * 256;            // threads covering one tensor
    int i = blk * 256 + tid;

    float mn[8], mx[8];
    #pragma unroll
    for (int u = 0; u < 8; ++u) { mn[u] = INFINITY; mx[u] = -INFINITY; }

    for (; i + 7 * stride < n4; i += 8 * stride) {
        float4 v[8];
        #pragma unroll
        for (int u = 0; u < 8; ++u) v[u] = p[i + u * stride];
        #pragma unroll
        for (int u = 0; u < 8; ++u) {
            mn[u] = fminf(mn[u], min4(v[u]));
            mx[u] = fmaxf(mx[u], max4(v[u]));
        }
    }
    for (; i < n4; i += stride) {
        float4 v = p[i];
        mn[0] = fminf(mn[0], min4(v));
        mx[0] = fmaxf(mx[0], max4(v));
    }
    #pragma unroll
    for (int u = 4; u < 8; ++u) { mn[u - 4] = fminf(mn[u - 4], mn[u]); mx[u - 4] = fmaxf(mx[u - 4], mx[u]); }
    float mnt = fminf(fminf(mn[0], mn[1]), fminf(mn[2], mn[3]));
    float mxt = fmaxf(fmaxf(mx[0], mx[1]), fmaxf(mx[2], mx[3]));

    for (int off = 32; off > 0; off >>= 1) {
        mnt = fminf(mnt, __shfl_down(mnt, off));
        mxt = fmaxf(mxt, __shfl_down(mxt, off));
    }
    __shared__ float red[4][2];
    int wv = tid >> 6;
    if ((tid & 63) == 0) { red[wv][0] = mnt; red[wv][1] = mxt; }
    __syncthreads();
    if (tid == 0) {
        part[2 * bid + 0] = __float_as_uint(fminf(fminf(red[0][0], red[1][0]), fminf(red[2][0], red[3][0])));
        part[2 * bid + 1] = __float_as_uint(fmaxf(fmaxf(red[0][1], red[1][1]), fmaxf(red[2][1], red[3][1])));
    }
}

// Pass 1b: one block reduces the 2*NBLK_T partial pairs -> ws[0..3].
__global__ __launch_bounds__(256) void minmax_reduce_kernel(const unsigned int* __restrict__ part,
                                                            unsigned int* __restrict__ ws) {
    int tid = threadIdx.x;
    float mna = INFINITY, mxa = -INFINITY, mnb = INFINITY, mxb = -INFINITY;
    for (int j = tid; j < NBLK_T; j += blockDim.x) {
        mna = fminf(mna, __uint_as_float(part[2 * j + 0]));
        mxa = fmaxf(mxa, __uint_as_float(part[2 * j + 1]));
        mnb = fminf(mnb, __uint_as_float(part[2 * (NBLK_T + j) + 0]));
        mxb = fmaxf(mxb, __uint_as_float(part[2 * (NBLK_T + j) + 1]));
    }
    for (int off = 32; off > 0; off >>= 1) {
        mna = fminf(mna, __shfl_down(mna, off));
        mxa = fmaxf(mxa, __shfl_down(mxa, off));
        mnb = fminf(mnb, __shfl_down(mnb, off));
        mxb = fmaxf(mxb, __shfl_down(mxb, off));
    }
    __shared__ float red[4][4];
    int wv = tid >> 6;
    if ((tid & 63) == 0) {
        red[wv][0] = mna; red[wv][1] = mxa; red[wv][2] = mnb; red[wv][3] = mxb;
    }
    __syncthreads();
    if (tid == 0) {
        ws[0] = __float_as_uint(fminf(fminf(red[0][0], red[1][0]), fminf(red[2][0], red[3][0])));
        ws[1] = __float_as_uint(fmaxf(fmaxf(red[0][1], red[1][1]), fmaxf(red[2][1], red[3][1])));
        ws[2] = __float_as_uint(fminf(fminf(red[0][2], red[1][2]), fminf(red[2][2], red[3][2])));
        ws[3] = __float_as_uint(fmaxf(fmaxf(red[0][3], red[1][3]), fmaxf(red[2][3], red[3][3])));
    }
}

__device__ __forceinline__ int bin_of(float x, float mn, float rg) {
    float d = (x - mn) / rg;          // IEEE div: matches jnp/np float32 normalize
    int bi = (int)floorf(d * 256.0f); // floor(img * bins)
    bi = bi < 0 ? 0 : bi;
    bi = bi > (BINS - 1) ? (BINS - 1) : bi;
    return bi;
}

__global__ __launch_bounds__(256) void hist_kernel(const float4* __restrict__ a,
                                                   const float4* __restrict__ b,
                                                   int n4, unsigned int* ws) {
    __shared__ unsigned int ha[4][NHIST];  // per-wave private copies
    __shared__ unsigned int hb[4][NHIST];
    int tid = threadIdx.x;
    int wv  = tid >> 6;
    for (int j = tid; j < 4 * NHIST; j += blockDim.x) {
        (&ha[0][0])[j] = 0u;
        (&hb[0][0])[j] = 0u;
    }
    __syncthreads();

    float mn_a = __uint_as_float(ws[0]);
    float rg_a = __uint_as_float(ws[1]) - mn_a;
    float mn_b = __uint_as_float(ws[2]);
    float rg_b = __uint_as_float(ws[3]) - mn_b;

    int stride = gridDim.x * blockDim.x;
    for (int i = blockIdx.x * blockDim.x + tid; i < n4; i += stride) {
        float4 va = a[i];
        float4 vb = b[i];
        int c = (i >> HW_LOG2_V4) % 3;   // all 4 elements share one channel
        unsigned int* HA = &ha[wv][c * BINS];
        unsigned int* HB = &hb[wv][c * BINS];
        atomicAdd(&HA[bin_of(va.x, mn_a, rg_a)], 1u);
        atomicAdd(&HA[bin_of(va.y, mn_a, rg_a)], 1u);
        atomicAdd(&HA[bin_of(va.z, mn_a, rg_a)], 1u);
        atomicAdd(&HA[bin_of(va.w, mn_a, rg_a)], 1u);
        atomicAdd(&HB[bin_of(vb.x, mn_b, rg_b)], 1u);
        atomicAdd(&HB[bin_of(vb.y, mn_b, rg_b)], 1u);
        atomicAdd(&HB[bin_of(vb.z, mn_b, rg_b)], 1u);
        atomicAdd(&HB[bin_of(vb.w, mn_b, rg_b)], 1u);
    }
    __syncthreads();

    // 8-way copy split: per-address atomic contention stays low
    unsigned int* dst = &ws[WS_HIST + (blockIdx.x & (NCOPY - 1)) * 2 * NHIST];
    for (int j = tid; j < NHIST; j += blockDim.x) {
        unsigned int sa = ha[0][j] + ha[1][j] + ha[2][j] + ha[3][j];
        unsigned int sb = hb[0][j] + hb[1][j] + hb[2][j] + hb[3][j];
        if (sa) atomicAdd(&dst[j], sa);
        if (sb) atomicAdd(&dst[NHIST + j], sb);
    }
}

__global__ __launch_bounds__(256) void finalize_kernel(const unsigned int* __restrict__ ws,
                                                       float* __restrict__ out) {
    __shared__ float sred[4];
    int tid = threadIdx.x;
    float s = 0.0f;
    for (int j = tid; j < NHIST; j += blockDim.x) {
        unsigned int sa = 0u, sb = 0u;
        for (int c = 0; c < NCOPY; ++c) {
            sa += ws[WS_HIST + c * 2 * NHIST + j];
            sb += ws[WS_HIST + c * 2 * NHIST + NHIST + j];
        }
        float d = (float)sa - (float)sb;
        s += d * d;
    }
    for (int off = 32; off > 0; off >>= 1) s += __shfl_down(s, off);
    if ((tid & 63) == 0) sred[tid >> 6] = s;
    __syncthreads();
    if (tid == 0) {
        float total = sred[0] + sred[1] + sred[2] + sred[3];
        float loss = total / (float)NHIST;          // jnp.mean over C*bins
        float r = 1.0f - 1.0f / loss;               // normalize_loss_output
        if (isinf(r)) r = 1.0f;
        out[0] = r;
    }
}

extern "C" void kernel_launch(void* const* d_in, const int* in_sizes, int n_in,
                              void* d_out, int out_size, void* d_ws, size_t ws_size,
                              hipStream_t stream) {
    const float4* a = (const float4*)d_in[0];
    const float4* b = (const float4*)d_in[1];
    unsigned int* ws = (unsigned int*)d_ws;
    float* out = (float*)d_out;
    int n  = in_sizes[0];        // 16*3*1024*1024 = 50331648
    int n4 = n >> 2;             // 12582912 float4s

    init_ws_kernel<<<16, 256, 0, stream>>>(ws);
    minmax_part_kernel<<<2 * NBLK_T, 256, 0, stream>>>(a, b, n4, &ws[WS_PART]);
    minmax_reduce_kernel<<<1, 256, 0, stream>>>(&ws[WS_PART], ws);
    hist_kernel<<<NBLK_H, 256, 0, stream>>>(a, b, n4, ws);
    finalize_kernel<<<1, 256, 0, stream>>>(ws, out);
}

// Round 4
// 85.741 us; speedup vs baseline: 1.8946x; 1.8946x over previous
//
#include <hip/hip_runtime.h>
#include <math.h>

#define BINS    256
#define CH      3
#define FB      512                   // fine bins over [0,1)
#define NFINE   (CH * FB)             // 1536 per tensor
#define NCOPY   8                     // global fine-hist copies (atomic contention split)
#define NBLK    1024                  // fused kernel blocks (4/CU)
#define HW_LOG2_V4 18                 // float4 idx -> plane idx (H*W = 1<<20, /4 = 1<<18)

// ws layout (uint):
//   [0 .. NCOPY*2*NFINE)        : fine-hist copies: copy c -> [a: NFINE][b: NFINE]
//   [WS_PART .. WS_PART+4*NBLK) : per-block minmax partials {mna,mxa,mnb,mxb}
#define WS_PART (NCOPY * 2 * NFINE)   // 24576

__global__ void init_ws_kernel(unsigned int* ws) {
    int i = blockIdx.x * blockDim.x + threadIdx.x;
    for (int j = i; j < WS_PART; j += gridDim.x * blockDim.x)
        ws[j] = 0u;
}

__device__ __forceinline__ float min4(float4 v) { return fminf(fminf(v.x, v.y), fminf(v.z, v.w)); }
__device__ __forceinline__ float max4(float4 v) { return fmaxf(fmaxf(v.x, v.y), fmaxf(v.z, v.w)); }

__device__ __forceinline__ int finebin(float x) {
    int f = (int)floorf(x * (float)FB);
    f = f < 0 ? 0 : f;
    f = f > (FB - 1) ? (FB - 1) : f;
    return f;
}

// ONE pass over both tensors: 512-bin fine histogram over [0,1) per channel
// (rebinned exactly later using true min/max) + per-block min/max partials.
// Loop structure cloned from the empirically-fast hist_kernel (plain
// grid-stride, 2 loads/iter, no unroll — R1/R3 unrolled minmax was 4x slower).
__global__ __launch_bounds__(256) void fused_kernel(const float4* __restrict__ a,
                                                    const float4* __restrict__ b,
                                                    int n4, unsigned int* ws) {
    __shared__ unsigned int ha[NFINE];
    __shared__ unsigned int hb[NFINE];
    int tid = threadIdx.x;
    for (int j = tid; j < NFINE; j += blockDim.x) { ha[j] = 0u; hb[j] = 0u; }
    __syncthreads();

    float mna = INFINITY, mxa = -INFINITY, mnb = INFINITY, mxb = -INFINITY;
    int stride = NBLK * 256;
    for (int i = blockIdx.x * 256 + tid; i < n4; i += stride) {
        float4 va = a[i];
        float4 vb = b[i];
        int c = (i >> HW_LOG2_V4) % 3;       // all 4 elements share one channel plane
        unsigned int* HA = &ha[c * FB];
        unsigned int* HB = &hb[c * FB];
        mna = fminf(mna, min4(va));  mxa = fmaxf(mxa, max4(va));
        mnb = fminf(mnb, min4(vb));  mxb = fmaxf(mxb, max4(vb));
        atomicAdd(&HA[finebin(va.x)], 1u);
        atomicAdd(&HA[finebin(va.y)], 1u);
        atomicAdd(&HA[finebin(va.z)], 1u);
        atomicAdd(&HA[finebin(va.w)], 1u);
        atomicAdd(&HB[finebin(vb.x)], 1u);
        atomicAdd(&HB[finebin(vb.y)], 1u);
        atomicAdd(&HB[finebin(vb.z)], 1u);
        atomicAdd(&HB[finebin(vb.w)], 1u);
    }

    // block min/max partials (no global atomics)
    for (int off = 32; off > 0; off >>= 1) {
        mna = fminf(mna, __shfl_down(mna, off));
        mxa = fmaxf(mxa, __shfl_down(mxa, off));
        mnb = fminf(mnb, __shfl_down(mnb, off));
        mxb = fmaxf(mxb, __shfl_down(mxb, off));
    }
    __shared__ float red[4][4];
    int wv = tid >> 6;
    if ((tid & 63) == 0) {
        red[wv][0] = mna; red[wv][1] = mxa; red[wv][2] = mnb; red[wv][3] = mxb;
    }
    __syncthreads();
    if (tid == 0) {
        unsigned int* p = &ws[WS_PART + 4 * blockIdx.x];
        p[0] = __float_as_uint(fminf(fminf(red[0][0], red[1][0]), fminf(red[2][0], red[3][0])));
        p[1] = __float_as_uint(fmaxf(fmaxf(red[0][1], red[1][1]), fmaxf(red[2][1], red[3][1])));
        p[2] = __float_as_uint(fminf(fminf(red[0][2], red[1][2]), fminf(red[2][2], red[3][2])));
        p[3] = __float_as_uint(fmaxf(fmaxf(red[0][3], red[1][3]), fmaxf(red[2][3], red[3][3])));
    }
    __syncthreads();

    // flush fine hist to one of NCOPY global copies: per-address depth NBLK/NCOPY=128
    unsigned int* dst = &ws[(blockIdx.x & (NCOPY - 1)) * 2 * NFINE];
    for (int j = tid; j < NFINE; j += blockDim.x) {
        unsigned int sa = ha[j], sb = hb[j];
        if (sa) atomicAdd(&dst[j], sa);
        if (sb) atomicAdd(&dst[NFINE + j], sb);
    }
}

// Reduce partials -> exact min/max; rebin fine(512)->final(256) per channel via
// the reference mapping applied to fine-bin centers (exact: every reference bin
// edge is within ~1 ulp of a fine boundary since min~1e-8, max~1-1e-8);
// then MSE over 768 bins and the 1 - 1/loss epilogue.
__global__ __launch_bounds__(256) void rebin_finalize_kernel(const unsigned int* __restrict__ ws,
                                                             float* __restrict__ out) {
    int tid = threadIdx.x;
    // 1) min/max reduce over NBLK partials
    float mna = INFINITY, mxa = -INFINITY, mnb = INFINITY, mxb = -INFINITY;
    const unsigned int* part = &ws[WS_PART];
    for (int j = tid; j < NBLK; j += blockDim.x) {
        mna = fminf(mna, __uint_as_float(part[4 * j + 0]));
        mxa = fmaxf(mxa, __uint_as_float(part[4 * j + 1]));
        mnb = fminf(mnb, __uint_as_float(part[4 * j + 2]));
        mxb = fmaxf(mxb, __uint_as_float(part[4 * j + 3]));
    }
    for (int off = 32; off > 0; off >>= 1) {
        mna = fminf(mna, __shfl_down(mna, off));
        mxa = fmaxf(mxa, __shfl_down(mxa, off));
        mnb = fminf(mnb, __shfl_down(mnb, off));
        mxb = fmaxf(mxb, __shfl_down(mxb, off));
    }
    __shared__ float red[4][4];
    int wv = tid >> 6;
    if ((tid & 63) == 0) {
        red[wv][0] = mna; red[wv][1] = mxa; red[wv][2] = mnb; red[wv][3] = mxb;
    }
    __syncthreads();
    __shared__ float mm[4];
    if (tid == 0) {
        mm[0] = fminf(fminf(red[0][0], red[1][0]), fminf(red[2][0], red[3][0]));
        mm[1] = fmaxf(fmaxf(red[0][1], red[1][1]), fmaxf(red[2][1], red[3][1]));
        mm[2] = fminf(fminf(red[0][2], red[1][2]), fminf(red[2][2], red[3][2]));
        mm[3] = fmaxf(fmaxf(red[0][3], red[1][3]), fmaxf(red[2][3], red[3][3]));
    }
    __shared__ unsigned int hin[CH * BINS];
    __shared__ unsigned int htg[CH * BINS];
    for (int j = tid; j < CH * BINS; j += blockDim.x) { hin[j] = 0u; htg[j] = 0u; }
    __syncthreads();

    float mn_a = mm[0], rg_a = mm[1] - mm[0];
    float mn_b = mm[2], rg_b = mm[3] - mm[2];

    // 2) merge copies + rebin
    for (int j = tid; j < NFINE; j += blockDim.x) {
        unsigned int sa = 0u, sb = 0u;
        for (int c = 0; c < NCOPY; ++c) {
            sa += ws[c * 2 * NFINE + j];
            sb += ws[c * 2 * NFINE + NFINE + j];
        }
        int ch = j / FB, f = j - ch * FB;
        float x = ((float)f + 0.5f) * (1.0f / (float)FB);   // fine-bin center
        int ia = (int)floorf((x - mn_a) / rg_a * (float)BINS);
        ia = ia < 0 ? 0 : (ia > BINS - 1 ? BINS - 1 : ia);
        int ib = (int)floorf((x - mn_b) / rg_b * (float)BINS);
        ib = ib < 0 ? 0 : (ib > BINS - 1 ? BINS - 1 : ib);
        if (sa) atomicAdd(&hin[ch * BINS + ia], sa);
        if (sb) atomicAdd(&htg[ch * BINS + ib], sb);
    }
    __syncthreads();

    // 3) MSE + epilogue
    float s = 0.0f;
    for (int j = tid; j < CH * BINS; j += blockDim.x) {
        float d = (float)hin[j] - (float)htg[j];
        s += d * d;
    }
    for (int off = 32; off > 0; off >>= 1) s += __shfl_down(s, off);
    __shared__ float sred[4];
    if ((tid & 63) == 0) sred[tid >> 6] = s;
    __syncthreads();
    if (tid == 0) {
        float total = sred[0] + sred[1] + sred[2] + sred[3];
        float loss = total / (float)(CH * BINS);    // jnp.mean
        float r = 1.0f - 1.0f / loss;               // normalize_loss_output
        if (isinf(r)) r = 1.0f;
        out[0] = r;
    }
}

extern "C" void kernel_launch(void* const* d_in, const int* in_sizes, int n_in,
                              void* d_out, int out_size, void* d_ws, size_t ws_size,
                              hipStream_t stream) {
    const float4* a = (const float4*)d_in[0];
    const float4* b = (const float4*)d_in[1];
    unsigned int* ws = (unsigned int*)d_ws;
    float* out = (float*)d_out;
    int n  = in_sizes[0];        // 16*3*1024*1024
    int n4 = n >> 2;

    init_ws_kernel<<<24, 256, 0, stream>>>(ws);
    fused_kernel<<<NBLK, 256, 0, stream>>>(a, b, n4, ws);
    rebin_finalize_kernel<<<1, 256, 0, stream>>>(ws, out);
}